// Round 11
// baseline (231.657 us; speedup 1.0000x reference)
//
#include <hip/hip_runtime.h>
#include <hip/hip_bf16.h>

// ---------------------------------------------------------------------------
// Fused MHA forward, MI355X (gfx950).
// cvt(x) -> bf16 ; merged LDS-tiled transposed cvt of W* ;
// fused GEMM {q=(x@WQ)*0.125*log2e, k=x@WK, vT=(x@WV)^T} (BM=128,BN=128) ;
// flash attention (swapped-operand S^T=K Q^T, O^T=V^T P^T, lane-local exp2
// softmax, zero cross-lane ops on common path, ONE q-tile per block,
// 2048 blocks longest-first, 5 blocks/CU) ; out = concat @ WO (fp32).
// Sizes: H=16, DM=1024, DK=DV=64, N=4, L=2048, M=N*L=8192.
// LESSONS: R5/R6 raw-asm permlane = wrong semantics. R7 bias-as-C-init put
// mask load on pre-MFMA critical path. R9 shuffle-removal = +6us (chain was
// not shuffle-dominated). R10: occupancy was the limiter candidate — unpair
// q-tiles (R2's pairing halved block count; staging-share is cheap since
// K/V fills are L3-sourced), 1024->2048 blocks, 4->5 blocks/CU.
// ---------------------------------------------------------------------------

typedef unsigned short ushort_t;
typedef __bf16 bf16x8 __attribute__((ext_vector_type(8)));
typedef float  f32x4  __attribute__((ext_vector_type(4)));
typedef unsigned short us4 __attribute__((ext_vector_type(4)));
typedef short s16x4 __attribute__((ext_vector_type(4)));

__device__ __forceinline__ ushort_t f2bf(float f) {
    union { float f; unsigned u; } a; a.f = f;
    unsigned r = a.u + 0x7fffu + ((a.u >> 16) & 1u);   // RNE
    return (ushort_t)(r >> 16);
}

__device__ __forceinline__ void gload16(const ushort_t* g, ushort_t* l) {
    __builtin_amdgcn_global_load_lds(
        (const __attribute__((address_space(1))) void*)g,
        (__attribute__((address_space(3))) void*)l, 16, 0, 0);
}

// --------------------------- converters ------------------------------------
__global__ __launch_bounds__(256) void cvt_f32_bf16(const float* __restrict__ in,
                                                    ushort_t* __restrict__ out, int n4) {
    int i = blockIdx.x * 256 + threadIdx.x;
    if (i >= n4) return;
    float4 v = reinterpret_cast<const float4*>(in)[i];
    us4 o;
    o[0] = f2bf(v.x); o[1] = f2bf(v.y); o[2] = f2bf(v.z); o[3] = f2bf(v.w);
    reinterpret_cast<us4*>(out)[i] = o;
}

// out[b][c][r] = in[b][r][c], 32x32 LDS tile, both sides coalesced.
__global__ __launch_bounds__(256) void cvt_transpose32(const float* __restrict__ in,
                                                       ushort_t* __restrict__ out,
                                                       int R, int C) {
    const int b = blockIdx.z;
    const int c0 = blockIdx.x * 32, r0 = blockIdx.y * 32;
    const int tx = threadIdx.x & 31, ty = threadIdx.x >> 5;   // 8 rows/pass
    __shared__ ushort_t t[32][33];
    const float* ip = in + ((size_t)b * R + r0) * C + c0;
    #pragma unroll
    for (int i = 0; i < 4; ++i)
        t[ty + 8 * i][tx] = f2bf(ip[(size_t)(ty + 8 * i) * C + tx]);
    __syncthreads();
    ushort_t* op = out + ((size_t)b * C + c0) * R + r0;
    #pragma unroll
    for (int i = 0; i < 4; ++i)
        op[(size_t)(ty + 8 * i) * R + tx] = t[tx][ty + 8 * i];
}

// merged WQ/WK/WV transpose: z in [0,48), slab z%16 of {WQ,WK,WV}[z/16]
__global__ __launch_bounds__(256) void cvt_transpose_qkv(const float* __restrict__ WQ,
                                                         const float* __restrict__ WK,
                                                         const float* __restrict__ WV,
                                                         ushort_t* __restrict__ out) {
    const int z = blockIdx.z;
    const float* in = (z < 16) ? WQ : (z < 32) ? WK : WV;
    const int b = z & 15;                                    // slab within input
    const int c0 = blockIdx.x * 32, r0 = blockIdx.y * 32;    // R=1024, C=64
    const int tx = threadIdx.x & 31, ty = threadIdx.x >> 5;
    __shared__ ushort_t t[32][33];
    const float* ip = in + ((size_t)b * 1024 + r0) * 64 + c0;
    #pragma unroll
    for (int i = 0; i < 4; ++i)
        t[ty + 8 * i][tx] = f2bf(ip[(size_t)(ty + 8 * i) * 64 + tx]);
    __syncthreads();
    ushort_t* op = out + (size_t)z * 65536 + (size_t)c0 * 1024 + r0;
    #pragma unroll
    for (int i = 0; i < 4; ++i)
        op[(size_t)(ty + 8 * i) * 1024 + tx] = t[tx][ty + 8 * i];
}

// --------------------------- GEMM (A[M][1024] @ BT[N'][1024]^T) -------------
// BM=128, BN=128, BK=64, 256 threads / 4 waves (2x2), 4x4 frags per wave.
// MODE 3: fused QKV. Per-fragment slab s = 2*by + (col>>6):
//         s<16 -> q (bf16, scaled); s<32 -> k (bf16); s>=32 -> vT store.
// MODE 2: fp32 out at Cout[m*1024 + by*128 + col]             (final)
template<int MODE>
__global__ __launch_bounds__(256, 2)
void gemm_bt(const ushort_t* __restrict__ Ag, const ushort_t* __restrict__ BT,
             void* __restrict__ Cout, float scale) {
    const int bm = blockIdx.x, by = blockIdx.y;
    const int tid = threadIdx.x;
    const int w = tid >> 6, lane = tid & 63;
    const int wr = w >> 1, wc = w & 1;
    const int g = lane >> 4, c = lane & 15;
    const int m0 = bm * 128;
    const ushort_t* Bbase = BT + (size_t)by * 131072;   // 128*1024

    __shared__ __align__(16) ushort_t As[128 * 64];    // 16 KB, swizzled
    __shared__ __align__(16) ushort_t Bs[128 * 64];    // 16 KB, swizzled

    f32x4 acc[4][4];
    #pragma unroll
    for (int i = 0; i < 4; ++i)
        #pragma unroll
        for (int j = 0; j < 4; ++j) acc[i][j] = (f32x4){0.f, 0.f, 0.f, 0.f};

    const int rsub = (w << 3) + (lane >> 3);   // 0..31
    const int s8   = lane & 7;

    for (int t = 0; t < 16; ++t) {
        const int k0 = t * 64;
        #pragma unroll
        for (int is = 0; is < 4; ++is) {
            const int row = is * 32 + rsub;
            const int sg  = (s8 ^ (row & 7)) << 3;
            gload16(Ag + (size_t)(m0 + row) * 1024 + k0 + sg, &As[is * 2048 + w * 512]);
            gload16(Bbase + (size_t)row * 1024 + k0 + sg,     &Bs[is * 2048 + w * 512]);
        }
        __syncthreads();
        #pragma unroll
        for (int kk = 0; kk < 2; ++kk) {
            bf16x8 af[4], bfr[4];
            #pragma unroll
            for (int mf = 0; mf < 4; ++mf) {
                const int row = wr * 64 + mf * 16 + c;
                const int slot = (kk * 4 + g) ^ (row & 7);
                af[mf] = *reinterpret_cast<const bf16x8*>(&As[row * 64 + slot * 8]);
            }
            #pragma unroll
            for (int nf = 0; nf < 4; ++nf) {
                const int row = wc * 64 + nf * 16 + c;
                const int slot = (kk * 4 + g) ^ (row & 7);
                bfr[nf] = *reinterpret_cast<const bf16x8*>(&Bs[row * 64 + slot * 8]);
            }
            __builtin_amdgcn_s_setprio(1);
            #pragma unroll
            for (int mf = 0; mf < 4; ++mf)
                #pragma unroll
                for (int nf = 0; nf < 4; ++nf)
                    acc[mf][nf] = __builtin_amdgcn_mfma_f32_16x16x32_bf16(
                        af[mf], bfr[nf], acc[mf][nf], 0, 0, 0);
            __builtin_amdgcn_s_setprio(0);
        }
        __syncthreads();
    }

    #pragma unroll
    for (int mf = 0; mf < 4; ++mf) {
        const int mbase = m0 + wr * 64 + mf * 16 + g * 4;
        #pragma unroll
        for (int nf = 0; nf < 4; ++nf) {
            const int colG = wc * 64 + nf * 16 + c;
            if (MODE == 3) {
                const int s  = by * 2 + (colG >> 6);
                const int c2 = colG & 63;
                ushort_t* o = (ushort_t*)Cout + (size_t)s * 524288;
                if (s < 32) {
                    const float scl = (s < 16) ? scale : 1.0f;
                    #pragma unroll
                    for (int r = 0; r < 4; ++r)
                        o[(size_t)(mbase + r) * 64 + c2] = f2bf(acc[mf][nf][r] * scl);
                } else {
                    us4 pk;
                    #pragma unroll
                    for (int r = 0; r < 4; ++r) pk[r] = f2bf(acc[mf][nf][r]);
                    const int nIdx = mbase >> 11, l = mbase & 2047;
                    *reinterpret_cast<us4*>(
                        &o[(size_t)nIdx * 131072 + (size_t)c2 * 2048 + l]) = pk;
                }
            } else {
                float* o = (float*)Cout;
                #pragma unroll
                for (int r = 0; r < 4; ++r)
                    o[(size_t)(mbase + r) * 1024 + by * 128 + colG] = acc[mf][nf][r];
            }
        }
    }
}

// --------------------------- flash attention --------------------------------
// grid (32, N, H), 256 thr / 4 waves, ONE q-tile per block (qblk = 31-bx so
// longest causal blocks dispatch first). 5 blocks/CU (LDS 32KB).
// qrow = q0 + (lane&15) is lane-local; softmax in exp2 domain (q pre-scaled
// by 0.125*log2e); defer-max THR=8 gated on LANE-LOCAL max; lrun kept
// lane-partial (reduced at epilogue); P packed via v_cvt_pk_bf16_f32.
__global__ __launch_bounds__(256, 5)
void attn_kernel(const ushort_t* __restrict__ qb, const ushort_t* __restrict__ kb,
                 const ushort_t* __restrict__ vtb, const float* __restrict__ mi,
                 ushort_t* __restrict__ cat) {
    const int qblk = 31 - blockIdx.x;             // longest first
    const int n = blockIdx.y, h = blockIdx.z;
    const int tid = threadIdx.x;
    const int w = tid >> 6, lane = tid & 63;
    const int g = lane >> 4, c = lane & 15;
    const int q0 = qblk * 64 + w * 16;

    const ushort_t* qhn = qb  + (size_t)h * 524288 + (size_t)n * 131072;  // [2048][64]
    const ushort_t* khn = kb  + (size_t)h * 524288 + (size_t)n * 131072;  // [2048][64]
    const ushort_t* vhn = vtb + (size_t)h * 524288 + (size_t)n * 131072;  // [64][2048]
    const float*    mrow = mi + (size_t)n * 2048;

    __shared__ __align__(16) ushort_t Ks[2][64 * 64];  // 16 KB (swizzled)
    __shared__ __align__(16) ushort_t Vs[2][64 * 64];  // 16 KB

    const int rsub = (w << 3) + (lane >> 3);   // 0..31
    const int s8   = lane & 7;

    auto stage = [&](int jb, int b) {
        const int kbase = jb * 64;
        #pragma unroll
        for (int is = 0; is < 2; ++is) {
            const int row = is * 32 + rsub;
            const int sg  = (s8 ^ (row & 7)) << 3;
            gload16(khn + (size_t)(kbase + row) * 64 + sg, &Ks[b][is * 2048 + w * 512]);
            gload16(vhn + (size_t)row * 2048 + kbase + sg, &Vs[b][is * 2048 + w * 512]);
        }
    };

    // Q B-frags: qf[kk] = Q[q0 + c][kk*32 + g*8 .. +7]
    bf16x8 qf[2];
    {
        const ushort_t* qa = qhn + (size_t)(q0 + c) * 64 + g * 8;
        qf[0] = *reinterpret_cast<const bf16x8*>(qa);
        qf[1] = *reinterpret_cast<const bf16x8*>(qa + 32);
    }
    const float mq = mrow[q0 + c];

    // mrun: q-row-uniform; lrun: LANE-PARTIAL (reduced at epilogue)
    float mrun = -1e30f, lrun = 0.f;
    f32x4 acc[4];
    #pragma unroll
    for (int i = 0; i < 4; ++i) acc[i] = (f32x4){0.f, 0.f, 0.f, 0.f};

    stage(0, 0);
    __syncthreads();
    int buf = 0;

    for (int j = 0; j <= qblk; ++j) {
        if (j < qblk) stage(j + 1, buf ^ 1);
        const int kbase = j * 64;
        const bool diag = (j == qblk);
        // per-tile additive pad-mask bias (issued early, consumed post-MFMA)
        f32x4 bias;
        {
            float4 mk0 = *reinterpret_cast<const float4*>(&mrow[kbase + g * 4]);
            bias[0] = (mk0.x == 0.f) ? -1e30f : 0.f;
            bias[1] = (mk0.y == 0.f) ? -1e30f : 0.f;
            bias[2] = (mk0.z == 0.f) ? -1e30f : 0.f;
            bias[3] = (mk0.w == 0.f) ? -1e30f : 0.f;
        }
        f32x4 bias2[3];
        #pragma unroll
        for (int nf = 1; nf < 4; ++nf) {
            float4 mk = *reinterpret_cast<const float4*>(&mrow[kbase + nf * 16 + g * 4]);
            bias2[nf - 1][0] = (mk.x == 0.f) ? -1e30f : 0.f;
            bias2[nf - 1][1] = (mk.y == 0.f) ? -1e30f : 0.f;
            bias2[nf - 1][2] = (mk.z == 0.f) ? -1e30f : 0.f;
            bias2[nf - 1][3] = (mk.w == 0.f) ? -1e30f : 0.f;
        }

        // ---- S^T = K @ Q^T : 8 x mfma 16x16x32 (exp2 domain) ----
        f32x4 s[4];
        #pragma unroll
        for (int nf = 0; nf < 4; ++nf) s[nf] = (f32x4){0.f, 0.f, 0.f, 0.f};
        __builtin_amdgcn_s_setprio(1);
        #pragma unroll
        for (int kk = 0; kk < 2; ++kk)
            #pragma unroll
            for (int nf = 0; nf < 4; ++nf) {
                const int row  = nf * 16 + c;
                const int byte = row * 128 + (((kk * 4 + g) ^ (c & 7)) << 4);
                bf16x8 kf = *reinterpret_cast<const bf16x8*>(
                    reinterpret_cast<const char*>(&Ks[buf][0]) + byte);
                s[nf] = __builtin_amdgcn_mfma_f32_16x16x32_bf16(
                    kf, qf[kk], s[nf], 0, 0, 0);
            }
        __builtin_amdgcn_s_setprio(0);
        // ---- mask: pad bias (per tile) + causal (diag tile only) ----
        s[0] += bias;
        #pragma unroll
        for (int nf = 1; nf < 4; ++nf) s[nf] += bias2[nf - 1];
        if (diag) {
            const int qrow = q0 + c;
            #pragma unroll
            for (int nf = 0; nf < 4; ++nf)
                #pragma unroll
                for (int r = 0; r < 4; ++r)
                    if (kbase + nf * 16 + g * 4 + r > qrow) s[nf][r] = -1e30f;
        }
        // ---- lane-local max; cross-lane reduce ONLY on threshold breach ----
        float m01[4], m23[4];
        #pragma unroll
        for (int r = 0; r < 4; ++r) {
            m01[r] = fmaxf(s[0][r], s[1][r]);
            m23[r] = fmaxf(s[2][r], s[3][r]);
        }
        const float mtl = fmaxf(fmaxf(fmaxf(m01[0], m01[1]), fmaxf(m01[2], m01[3])),
                                fmaxf(fmaxf(m23[0], m23[1]), fmaxf(m23[2], m23[3])));
        if (!__all(mtl - mrun <= 8.0f)) {
            float mt = fmaxf(mtl, __shfl_xor(mtl, 16));
            mt = fmaxf(mt, __shfl_xor(mt, 32));
            const float mnew = fmaxf(mrun, mt);
            const float sc = __builtin_amdgcn_exp2f(mrun - mnew);
            #pragma unroll
            for (int nfd = 0; nfd < 4; ++nfd)
                #pragma unroll
                for (int r = 0; r < 4; ++r) acc[nfd][r] *= sc;
            lrun *= sc;                       // lane-partial, sc row-uniform
            mrun = mnew;
        }
        // ---- exp2 + bf16 pack; sum stays lane-partial (no shuffles) ----
        float rs = 0.f;
        union { unsigned u[2]; s16x4 v; } pb[4];
        #pragma unroll
        for (int nf = 0; nf < 4; ++nf) {
            const float p0 = __builtin_amdgcn_exp2f(s[nf][0] - mrun);
            const float p1 = __builtin_amdgcn_exp2f(s[nf][1] - mrun);
            const float p2 = __builtin_amdgcn_exp2f(s[nf][2] - mrun);
            const float p3 = __builtin_amdgcn_exp2f(s[nf][3] - mrun);
            rs += (p0 + p1) + (p2 + p3);
            asm("v_cvt_pk_bf16_f32 %0, %1, %2" : "=v"(pb[nf].u[0]) : "v"(p0), "v"(p1));
            asm("v_cvt_pk_bf16_f32 %0, %1, %2" : "=v"(pb[nf].u[1]) : "v"(p2), "v"(p3));
        }
        lrun += rs;
        // ---- O^T += V^T @ P^T : 16 x mfma 16x16x16 (P in registers) ----
        __builtin_amdgcn_s_setprio(1);
        #pragma unroll
        for (int kk = 0; kk < 4; ++kk)
            #pragma unroll
            for (int nfd = 0; nfd < 4; ++nfd) {
                const int row   = nfd * 16 + c;
                const int chunk = (kk * 2 + (g >> 1)) ^ (c & 7);
                const int byt   = row * 128 + (chunk << 4) + (g & 1) * 8;
                s16x4 vf = *reinterpret_cast<const s16x4*>(
                    reinterpret_cast<const char*>(&Vs[buf][0]) + byt);
                acc[nfd] = __builtin_amdgcn_mfma_f32_16x16x16bf16_1k(
                    vf, pb[kk].v, acc[nfd], 0, 0, 0);
            }
        __builtin_amdgcn_s_setprio(0);

        __syncthreads();
        buf ^= 1;
    }

    // ---- epilogue: reduce lane-partial lrun, O^T/l -> concat (bf16) ----
    {
        float lt = lrun;
        lt += __shfl_xor(lt, 16);
        lt += __shfl_xor(lt, 32);
        const float inv = (mq != 0.f && mrun > -1e29f && lt > 0.f)
                              ? (1.0f / lt) : 0.f;
        const size_t base = (size_t)(n * 2048 + q0 + c) * 1024 + h * 64;
        #pragma unroll
        for (int nfd = 0; nfd < 4; ++nfd) {
            us4 pk;
            #pragma unroll
            for (int r = 0; r < 4; ++r) pk[r] = f2bf(acc[nfd][r] * inv);
            *reinterpret_cast<us4*>(&cat[base + nfd * 16 + g * 4]) = pk;
        }
    }
}

// --------------------------- launcher ---------------------------------------
extern "C" void kernel_launch(void* const* d_in, const int* in_sizes, int n_in,
                              void* d_out, int out_size, void* d_ws, size_t ws_size,
                              hipStream_t stream) {
    const float* x  = (const float*)d_in[0];
    const float* mi = (const float*)d_in[1];
    const float* WQ = (const float*)d_in[2];
    const float* WK = (const float*)d_in[3];
    const float* WV = (const float*)d_in[4];
    const float* WO = (const float*)d_in[5];
    float* out = (float*)d_out;

    ushort_t* ws  = (ushort_t*)d_ws;
    ushort_t* xb  = ws;                    // 8192*1024           = 8388608
    ushort_t* wqt = xb  + 8388608;         // 48 slabs of 64*1024 (wq/wk/wv)
    ushort_t* wot = wqt + 3145728;         // 1024*1024           = 1048576
    ushort_t* qb  = wot + 1048576;         // [16][4][2048][64]   = 8388608
    ushort_t* kb  = qb  + 8388608;         // (qb/kb/vtb contiguous)
    ushort_t* vtb = kb  + 8388608;         // [16][4][64][2048]
    ushort_t* cat = xb;                    // reuse xb after QKV GEMM (16 MB)

    cvt_f32_bf16<<<8192, 256, 0, stream>>>(x, xb, 2097152);
    {
        dim3 gt(2, 32, 48);                // C/32, R/32, 48 slabs
        cvt_transpose_qkv<<<gt, 256, 0, stream>>>(WQ, WK, WV, wqt);
        dim3 go(32, 32, 1);
        cvt_transpose32<<<go, 256, 0, stream>>>(WO, wot, 1024, 1024);
    }

    // fused QKV: slabs 0-15 q (scaled 0.125*log2e), 16-31 k, 32-47 vT
    dim3 g1(64, 24);
    gemm_bt<3><<<g1, 256, 0, stream>>>(xb, wqt, qb, 0.18033688f);

    dim3 g2(32, 4, 16);
    attn_kernel<<<g2, 256, 0, stream>>>(qb, kb, vtb, mi, cat);

    dim3 g3(64, 8);
    gemm_bt<2><<<g3, 256, 0, stream>>>(cat, wot, out, 1.0f);   // out fp32
}